// Round 6
// baseline (380.768 us; speedup 1.0000x reference)
//
#include <hip/hip_runtime.h>
#include <hip/hip_cooperative_groups.h>
#include <cmath>

namespace cg = cooperative_groups;

// Problem constants
#define SS 8192
#define BB 64
#define CHKA 32         // samples per chunk (per block)
#define NCHK 256        // SS / CHKA

// ws float offsets
#define O_LC   0u        // lc  [SS][64]   dt * chunk-local inclusive cumsum
#define O_TC   524288u   // Tc  [NCHK][64] dt * chunk total
#define O_LS   540672u   // Ls  [NCHK][64] sum over chunk of lc
#define O_OFF  557056u   // off [NCHK][64] exclusive scan of Tc
#define O_GD   573440u   // Gd  [64]
#define O_HS   573504u   // hsts[12][64]

// smem float offsets (total 29152 floats = 116608 B -> 1 block/CU)
#define SM_W2  0         // 64*128
#define SM_W3  8192      // 128*64
#define SM_W4  16384     // 64*64
#define SM_W1  20480
#define SM_B1  20544
#define SM_B2  20608
#define SM_B3  20736
#define SM_B4  20800
#define SM_HA  20864     // 32 x 65  (h1, later rhs R)
#define SM_XB  22944     // 32 x 129 (h2)
#define SM_XC  27072     // 32 x 65  (h3)
#define SM_TOTAL 29152
// phase B overlay (block 0): gsum [8][65] @0, offL [64] @520
// phase D overlay (blocks<64): tot@0, sy0@64, shts@128, V@896, feat@2560

__global__ __launch_bounds__(512) void k_all(
    const float* __restrict__ t, const float* __restrict__ y0,
    const float* __restrict__ W1, const float* __restrict__ b1,
    const float* __restrict__ W2, const float* __restrict__ b2,
    const float* __restrict__ W3, const float* __restrict__ b3,
    const float* __restrict__ W4, const float* __restrict__ b4,
    const float* __restrict__ K3, const float* __restrict__ c3,
    const float* __restrict__ K5, const float* __restrict__ c5,
    const float* __restrict__ K7, const float* __restrict__ c7,
    const float* __restrict__ K11, const float* __restrict__ c11,
    const float* __restrict__ H1, const float* __restrict__ hb1,
    const float* __restrict__ H2, const float* __restrict__ hb2,
    float* __restrict__ ws, float* __restrict__ out)
{
    __shared__ float sm[SM_TOTAL];
    const int tid = threadIdx.x;

    // ---------------- Phase A: MLP rhs + chunk-local cumsum ----------------
    {
        for (int i = tid; i < 8192; i += 512) { sm[SM_W2 + i] = W2[i]; sm[SM_W3 + i] = W3[i]; }
        for (int i = tid; i < 4096; i += 512) sm[SM_W4 + i] = W4[i];
        if (tid < 64) { sm[SM_W1 + tid] = W1[tid]; sm[SM_B1 + tid] = b1[tid];
                        sm[SM_B3 + tid] = b3[tid]; sm[SM_B4 + tid] = b4[tid]; }
        else if (tid < 192) sm[SM_B2 + tid - 64] = b2[tid - 64];
        __syncthreads();

        const int q = tid >> 5, samp = tid & 31;   // 16 neuron-slices, 32 samples
        const int c = blockIdx.x;
        const int s = c * CHKA + samp;
        const float dtv = t[1] - t[0];
        const float tv = t[s];                     // t row 0 (identical across batch)

        // layer1: slice q owns cols q*4..q*4+3
        #pragma unroll
        for (int j = 0; j < 4; ++j) {
            const int col = q * 4 + j;
            sm[SM_HA + samp * 65 + col] = tanhf(fmaf(tv, sm[SM_W1 + col], sm[SM_B1 + col]));
        }
        __syncthreads();

        // layer2: slice q owns cols q*8..q*8+7
        float a2[8];
        #pragma unroll
        for (int j = 0; j < 8; ++j) a2[j] = sm[SM_B2 + q * 8 + j];
        for (int i = 0; i < 64; ++i) {
            const float h = sm[SM_HA + samp * 65 + i];
            #pragma unroll
            for (int j = 0; j < 8; ++j) a2[j] = fmaf(h, sm[SM_W2 + i * 128 + q * 8 + j], a2[j]);
        }
        #pragma unroll
        for (int j = 0; j < 8; ++j) sm[SM_XB + samp * 129 + q * 8 + j] = tanhf(a2[j]);
        __syncthreads();

        // layer3: slice q owns cols q*4..q*4+3
        float a3[4];
        #pragma unroll
        for (int j = 0; j < 4; ++j) a3[j] = sm[SM_B3 + q * 4 + j];
        for (int i = 0; i < 128; ++i) {
            const float h = sm[SM_XB + samp * 129 + i];
            #pragma unroll
            for (int j = 0; j < 4; ++j) a3[j] = fmaf(h, sm[SM_W3 + i * 64 + q * 4 + j], a3[j]);
        }
        __syncthreads();
        #pragma unroll
        for (int j = 0; j < 4; ++j) sm[SM_XC + samp * 65 + q * 4 + j] = tanhf(a3[j]);
        __syncthreads();

        // layer4: slice q owns cols q*4..q*4+3
        float a4[4];
        #pragma unroll
        for (int j = 0; j < 4; ++j) a4[j] = sm[SM_B4 + q * 4 + j];
        for (int i = 0; i < 64; ++i) {
            const float h = sm[SM_XC + samp * 65 + i];
            #pragma unroll
            for (int j = 0; j < 4; ++j) a4[j] = fmaf(h, sm[SM_W4 + i * 64 + q * 4 + j], a4[j]);
        }
        if (s == 0) {                               // rhs row 0 := 0 (cumsum starts at s=1)
            #pragma unroll
            for (int j = 0; j < 4; ++j) a4[j] = 0.f;
        }
        // write rhs R into HA (layer2 HA reads finished before XB barrier)
        #pragma unroll
        for (int j = 0; j < 4; ++j) sm[SM_HA + samp * 65 + q * 4 + j] = a4[j];
        __syncthreads();

        // chunk-local inclusive cumsum, dt-scaled (wave 0; lane = column)
        if (tid < 64) {
            const int col = tid;
            float run = 0.f, Ls = 0.f;
            for (int jj = 0; jj < CHKA; ++jj) {
                run += sm[SM_HA + jj * 65 + col];
                const float v = dtv * run;
                ws[O_LC + (c * CHKA + jj) * 64 + col] = v;
                Ls += v;
            }
            ws[O_TC + c * 64 + col] = dtv * run;
            ws[O_LS + c * 64 + col] = Ls;
        }
    }

    cg::this_grid().sync();

    // ---------------- Phase B: chunk-offset scan + Gd + head/tail (block 0) ----------------
    if (blockIdx.x == 0) {
        const int col = tid & 63, grp = tid >> 6;   // 8 groups x 32 chunks
        float Tl[32]; float tsum = 0.f;
        #pragma unroll
        for (int k = 0; k < 32; ++k) { Tl[k] = ws[O_TC + (grp * 32 + k) * 64 + col]; tsum += Tl[k]; }
        sm[grp * 65 + col] = tsum;
        __syncthreads();
        float base = 0.f;
        for (int g = 0; g < grp; ++g) base += sm[g * 65 + col];   // wave-uniform trip count
        __syncthreads();
        float run = base, gpart = 0.f;
        #pragma unroll
        for (int k = 0; k < 32; ++k) {
            const int cc = grp * 32 + k;
            ws[O_OFF + cc * 64 + col] = run;
            if (cc == NCHK - 1) sm[520 + col] = run;              // offL
            gpart += ws[O_LS + cc * 64 + col] + (float)CHKA * run;
            run += Tl[k];
        }
        sm[grp * 65 + col] = gpart;
        __syncthreads();
        if (grp == 0) {
            float g = 0.f;
            #pragma unroll
            for (int gg = 0; gg < 8; ++gg) g += sm[gg * 65 + col];
            ws[O_GD + col] = g;
        }
        if (grp == 1) {       // hs[d] = sum_{e<d} dtp[e]; chunk 0 -> dtp = lc
            float r2 = 0.f;
            ws[O_HS + col] = 0.f;
            for (int d = 1; d <= 5; ++d) { r2 += ws[O_LC + (d - 1) * 64 + col]; ws[O_HS + d * 64 + col] = r2; }
        }
        if (grp == 2) {       // ts[d] = sum_{e=1..d} dtp[S-e]; dtp = offL + lc
            const float oL = sm[520 + col];
            float r2 = 0.f;
            ws[O_HS + 6 * 64 + col] = 0.f;
            for (int d = 1; d <= 5; ++d) { r2 += oL + ws[O_LC + (SS - d) * 64 + col]; ws[O_HS + (6 + d) * 64 + col] = r2; }
        }
    }

    cg::this_grid().sync();

    // ---------------- Phase C: sol[b,s,:] = y0[b,:] + off[c(s),:] + lc[s,:] ----------------
    {
        const float4* lc4  = (const float4*)(ws + O_LC);
        const float4* off4 = (const float4*)(ws + O_OFF);
        const float4* y04  = (const float4*)y0;
        float4* out4 = (float4*)out;
        const int stride = 256 * 512;
        for (int idx = (int)blockIdx.x * 512 + tid; idx < BB * SS * 16; idx += stride) {
            const int i4 = idx & 15;
            const int s2 = (idx >> 4) & (SS - 1);
            const int b  = idx >> 17;
            const int cc = s2 >> 5;
            const float4 y = y04[b * 16 + i4];
            const float4 p = lc4[s2 * 16 + i4];
            const float4 f = off4[cc * 16 + i4];
            float4 o;
            o.x = y.x + f.x + p.x; o.y = y.y + f.y + p.y;
            o.z = y.z + f.z + p.z; o.w = y.w + f.w + p.w;
            out4[idx] = o;
        }
    }

    // ---------------- Phase D: analytic conv-mean features + hurst (blocks 0..63) ----------------
    if (blockIdx.x < BB) {
        __syncthreads();   // phase C has uniform trip count; reuse smem
        const int b = blockIdx.x;
        if (tid < 64) { sm[64 + tid] = y0[b * 64 + tid]; sm[tid] = (float)SS * sm[64 + tid] + ws[O_GD + tid]; }
        for (int n = tid; n < 768; n += 512) sm[128 + n] = ws[O_HS + n];
        __syncthreads();

        // V[n] = tot[i] - corr(d, i)
        for (int n = tid; n < 1664; n += 512) {
            int base2, k;
            if (n < 192)      { base2 = 0;   k = 3; }
            else if (n < 512) { base2 = 192; k = 5; }
            else if (n < 960) { base2 = 512; k = 7; }
            else              { base2 = 960; k = 11; }
            const int m = n - base2, i = m / k, j = m - i * k, d = j - (k >> 1);
            float corr = 0.f;
            if (d > 0)      corr = (float)d * sm[64 + i] + sm[128 + d * 64 + i];
            else if (d < 0) corr = (float)(-d) * sm[64 + i] + sm[128 + (6 - d) * 64 + i];
            sm[896 + n] = sm[i] - corr;
        }
        __syncthreads();

        const int wv = tid >> 6, lane = tid & 63;
        for (int qq = 0; qq < 8; ++qq) {
            const int o = wv * 8 + qq;
            float acc = 0.f;
            #pragma unroll
            for (int r = 0; r < 3; ++r)  { const int m = r * 64 + lane; acc = fmaf(K3[o * 192 + m],  sm[896 + m],       acc); }
            #pragma unroll
            for (int r = 0; r < 5; ++r)  { const int m = r * 64 + lane; acc = fmaf(K5[o * 320 + m],  sm[896 + 192 + m], acc); }
            #pragma unroll
            for (int r = 0; r < 7; ++r)  { const int m = r * 64 + lane; acc = fmaf(K7[o * 448 + m],  sm[896 + 512 + m], acc); }
            #pragma unroll
            for (int r = 0; r < 11; ++r) { const int m = r * 64 + lane; acc = fmaf(K11[o * 704 + m], sm[896 + 960 + m], acc); }
            #pragma unroll
            for (int d2 = 32; d2; d2 >>= 1) acc += __shfl_xor(acc, d2);
            if (lane == 0) {
                const float cb = c3[o] + c5[o] + c7[o] + c11[o];
                sm[2560 + o] = 0.25f * (acc * (1.0f / (float)SS) + cb);
            }
        }
        __syncthreads();

        if (tid < 64) {
            const int ln = tid;
            float g = hb1[ln];
            for (int o = 0; o < 64; ++o) g = fmaf(sm[2560 + o], H1[o * 64 + ln], g);
            g = fmaxf(g, 0.f);
            float v = g * H2[ln];
            #pragma unroll
            for (int d2 = 32; d2; d2 >>= 1) v += __shfl_xor(v, d2);
            if (ln == 0) out[(size_t)BB * SS * 64 + b] = 1.f / (1.f + expf(-(v + hb2[0])));
        }
    }
}

extern "C" void kernel_launch(void* const* d_in, const int* in_sizes, int n_in,
                              void* d_out, int out_size, void* d_ws, size_t ws_size,
                              hipStream_t stream)
{
    const float* t   = (const float*)d_in[0];
    const float* y0  = (const float*)d_in[1];
    const float* W1  = (const float*)d_in[2];
    const float* b1  = (const float*)d_in[3];
    const float* W2  = (const float*)d_in[4];
    const float* b2  = (const float*)d_in[5];
    const float* W3  = (const float*)d_in[6];
    const float* b3  = (const float*)d_in[7];
    const float* W4  = (const float*)d_in[8];
    const float* b4  = (const float*)d_in[9];
    const float* K3  = (const float*)d_in[10];
    const float* c3  = (const float*)d_in[11];
    const float* K5  = (const float*)d_in[12];
    const float* c5  = (const float*)d_in[13];
    const float* K7  = (const float*)d_in[14];
    const float* c7  = (const float*)d_in[15];
    const float* K11 = (const float*)d_in[16];
    const float* c11 = (const float*)d_in[17];
    const float* H1  = (const float*)d_in[18];
    const float* hb1 = (const float*)d_in[19];
    const float* H2  = (const float*)d_in[20];
    const float* hb2 = (const float*)d_in[21];

    float* out = (float*)d_out;
    float* ws  = (float*)d_ws;

    void* args[] = {
        (void*)&t, (void*)&y0,
        (void*)&W1, (void*)&b1, (void*)&W2, (void*)&b2,
        (void*)&W3, (void*)&b3, (void*)&W4, (void*)&b4,
        (void*)&K3, (void*)&c3, (void*)&K5, (void*)&c5,
        (void*)&K7, (void*)&c7, (void*)&K11, (void*)&c11,
        (void*)&H1, (void*)&hb1, (void*)&H2, (void*)&hb2,
        (void*)&ws, (void*)&out
    };
    hipLaunchCooperativeKernel((const void*)k_all, dim3(256), dim3(512), args, 0, stream);
}

// Round 10
// 292.088 us; speedup vs baseline: 1.3036x; 1.3036x over previous
//
#include <hip/hip_runtime.h>
#include <cmath>

// Problem constants
#define SS 8192
#define BB 64
#define CHKA 32         // samples per chunk (per k_rhs block)
#define NCHK 256        // SS / CHKA

typedef float __attribute__((ext_vector_type(4))) f32x4;

// ws float offsets
#define O_LC   0u        // lc  [SS][64]   dt * chunk-local inclusive cumsum
#define O_TC   524288u   // Tc  [NCHK][64] dt * chunk total
#define O_LS   540672u   // Ls  [NCHK][64] sum over chunk of lc
#define O_OFF  557056u   // off [NCHK][64] exclusive scan of Tc
#define O_GD   573440u   // Gd  [64]
#define O_HS   573504u   // hsts[12][64]

// k_rhs smem float offsets (29152 floats = 116608 B -> 1 block/CU, 8 waves)
#define SM_W2  0         // 64*128
#define SM_W3  8192      // 128*64
#define SM_W4  16384     // 64*64
#define SM_W1  20480
#define SM_B1  20544
#define SM_B2  20608
#define SM_B3  20736
#define SM_B4  20800
#define SM_HA  20864     // 32 x 65  (h1, later rhs R)
#define SM_XB  22944     // 32 x 129 (h2)
#define SM_XC  27072     // 32 x 65  (h3)
#define SM_TOTAL 29152

// ---------------- Kernel A: MLP rhs + chunk-local cumsum (256 blocks x 512) ----------------
__global__ __launch_bounds__(512) void k_rhs(
    const float* __restrict__ t,
    const float* __restrict__ W1, const float* __restrict__ b1,
    const float* __restrict__ W2, const float* __restrict__ b2,
    const float* __restrict__ W3, const float* __restrict__ b3,
    const float* __restrict__ W4, const float* __restrict__ b4,
    float* __restrict__ ws)
{
    __shared__ float sm[SM_TOTAL];
    const int tid = threadIdx.x;

    for (int i = tid; i < 8192; i += 512) { sm[SM_W2 + i] = W2[i]; sm[SM_W3 + i] = W3[i]; }
    for (int i = tid; i < 4096; i += 512) sm[SM_W4 + i] = W4[i];
    if (tid < 64) { sm[SM_W1 + tid] = W1[tid]; sm[SM_B1 + tid] = b1[tid];
                    sm[SM_B3 + tid] = b3[tid]; sm[SM_B4 + tid] = b4[tid]; }
    else if (tid < 192) sm[SM_B2 + tid - 64] = b2[tid - 64];
    __syncthreads();

    const int q = tid >> 5, samp = tid & 31;   // 16 neuron-slices x 32 samples
    const int c = blockIdx.x;
    const int s = c * CHKA + samp;
    const float dtv = t[1] - t[0];
    const float tv = t[s];                     // t row 0 (identical across batch)

    // layer1: slice q owns cols q*4..q*4+3
    #pragma unroll
    for (int j = 0; j < 4; ++j) {
        const int col = q * 4 + j;
        sm[SM_HA + samp * 65 + col] = tanhf(fmaf(tv, sm[SM_W1 + col], sm[SM_B1 + col]));
    }
    __syncthreads();

    // layer2: slice q owns cols q*8..q*8+7
    float a2[8];
    #pragma unroll
    for (int j = 0; j < 8; ++j) a2[j] = sm[SM_B2 + q * 8 + j];
    for (int i = 0; i < 64; ++i) {
        const float h = sm[SM_HA + samp * 65 + i];
        #pragma unroll
        for (int j = 0; j < 8; ++j) a2[j] = fmaf(h, sm[SM_W2 + i * 128 + q * 8 + j], a2[j]);
    }
    #pragma unroll
    for (int j = 0; j < 8; ++j) sm[SM_XB + samp * 129 + q * 8 + j] = tanhf(a2[j]);
    __syncthreads();

    // layer3: slice q owns cols q*4..q*4+3
    float a3[4];
    #pragma unroll
    for (int j = 0; j < 4; ++j) a3[j] = sm[SM_B3 + q * 4 + j];
    for (int i = 0; i < 128; ++i) {
        const float h = sm[SM_XB + samp * 129 + i];
        #pragma unroll
        for (int j = 0; j < 4; ++j) a3[j] = fmaf(h, sm[SM_W3 + i * 64 + q * 4 + j], a3[j]);
    }
    __syncthreads();
    #pragma unroll
    for (int j = 0; j < 4; ++j) sm[SM_XC + samp * 65 + q * 4 + j] = tanhf(a3[j]);
    __syncthreads();

    // layer4: slice q owns cols q*4..q*4+3
    float a4[4];
    #pragma unroll
    for (int j = 0; j < 4; ++j) a4[j] = sm[SM_B4 + q * 4 + j];
    for (int i = 0; i < 64; ++i) {
        const float h = sm[SM_XC + samp * 65 + i];
        #pragma unroll
        for (int j = 0; j < 4; ++j) a4[j] = fmaf(h, sm[SM_W4 + i * 64 + q * 4 + j], a4[j]);
    }
    if (s == 0) {                               // rhs row 0 := 0 (cumsum starts at s=1)
        #pragma unroll
        for (int j = 0; j < 4; ++j) a4[j] = 0.f;
    }
    #pragma unroll
    for (int j = 0; j < 4; ++j) sm[SM_HA + samp * 65 + q * 4 + j] = a4[j];
    __syncthreads();

    // chunk-local inclusive cumsum, dt-scaled (wave 0; lane = column)
    if (tid < 64) {
        const int col = tid;
        float run = 0.f, Ls = 0.f;
        for (int jj = 0; jj < CHKA; ++jj) {
            run += sm[SM_HA + jj * 65 + col];
            const float v = dtv * run;
            ws[O_LC + (c * CHKA + jj) * 64 + col] = v;
            Ls += v;
        }
        ws[O_TC + c * 64 + col] = dtv * run;
        ws[O_LS + c * 64 + col] = Ls;
    }
}

// ---------------- Kernel B: chunk-offset scan + Gd + head/tail (1 block x 1024) ----------------
__global__ __launch_bounds__(1024) void k_scan(float* __restrict__ ws)
{
    __shared__ float gsum[16 * 65];
    __shared__ float offL[64];
    const int tid = threadIdx.x;
    const int col = tid & 63, grp = tid >> 6;   // 16 groups x 16 chunks

    float Tl[16]; float tsum = 0.f;
    #pragma unroll
    for (int k = 0; k < 16; ++k) { Tl[k] = ws[O_TC + (grp * 16 + k) * 64 + col]; tsum += Tl[k]; }
    gsum[grp * 65 + col] = tsum;
    __syncthreads();

    float base = 0.f;
    for (int g = 0; g < grp; ++g) base += gsum[g * 65 + col];   // wave-uniform trip count
    __syncthreads();                                             // all reads done before overwrite

    float run = base, gpart = 0.f;
    #pragma unroll
    for (int k = 0; k < 16; ++k) {
        const int cc = grp * 16 + k;
        ws[O_OFF + cc * 64 + col] = run;
        if (cc == NCHK - 1) offL[col] = run;
        gpart += ws[O_LS + cc * 64 + col] + (float)CHKA * run;
        run += Tl[k];
    }
    gsum[grp * 65 + col] = gpart;
    __syncthreads();

    if (grp == 0) {
        float g = 0.f;
        #pragma unroll
        for (int gg = 0; gg < 16; ++gg) g += gsum[gg * 65 + col];
        ws[O_GD + col] = g;
    }
    if (grp == 1) {       // hs[d] = sum_{e<d} dtp[e]; chunk 0 offset = 0 -> dtp = lc
        float r2 = 0.f;
        ws[O_HS + col] = 0.f;
        for (int d = 1; d <= 5; ++d) { r2 += ws[O_LC + (d - 1) * 64 + col]; ws[O_HS + d * 64 + col] = r2; }
    }
    if (grp == 2) {       // ts[d] = sum_{e=1..d} dtp[S-e]; dtp = offL + lc
        const float oL = offL[col];
        float r2 = 0.f;
        ws[O_HS + 6 * 64 + col] = 0.f;
        for (int d = 1; d <= 5; ++d) { r2 += oL + ws[O_LC + (SS - d) * 64 + col]; ws[O_HS + (6 + d) * 64 + col] = r2; }
    }
}

// ---------------- Kernel C: sol[b,s,:] = y0[b,:] + off[c(s),:] + lc[s,:] ----------------
// 2048 blocks x 256. Thread owns one (s, i4); pf hoisted; walks 16 b-values
// with non-temporal stores (out stream bypasses L2, lc/off/y0 stay resident).
__global__ __launch_bounds__(256) void k_sol(const f32x4* __restrict__ y04,
                                             const f32x4* __restrict__ lc4,
                                             const f32x4* __restrict__ off4,
                                             f32x4* __restrict__ out4)
{
    const int gtid = blockIdx.x * 256 + threadIdx.x;   // 524288 threads
    const int si = gtid & 131071;                      // (s, i4): s = si>>4, i4 = si&15
    const int bg = gtid >> 17;                         // 0..3
    const int i4 = si & 15;
    const int s  = si >> 4;
    const f32x4 p = lc4[si];
    const f32x4 f = off4[(s >> 5) * 16 + i4];
    const f32x4 pf = p + f;
    #pragma unroll
    for (int k = 0; k < 16; ++k) {
        const int b = bg * 16 + k;
        const f32x4 o = y04[b * 16 + i4] + pf;
        __builtin_nontemporal_store(o, &out4[b * 131072 + si]);
    }
}

// ---------------- Kernel D: analytic conv-mean features + hurst (64 blocks x 256) ----------------
__global__ __launch_bounds__(256) void k_feat(
    const float* __restrict__ y0, const float* __restrict__ ws,
    const float* __restrict__ K3, const float* __restrict__ c3,
    const float* __restrict__ K5, const float* __restrict__ c5,
    const float* __restrict__ K7, const float* __restrict__ c7,
    const float* __restrict__ K11, const float* __restrict__ c11,
    const float* __restrict__ H1, const float* __restrict__ hb1,
    const float* __restrict__ H2, const float* __restrict__ hb2,
    float* __restrict__ hurst)
{
    __shared__ float tot[64], sy0[64], shts[12 * 64], V[1664], feat[64];
    const int b = blockIdx.x, tid = threadIdx.x;
    const int wv = tid >> 6, lane = tid & 63;

    if (tid < 64) { sy0[tid] = y0[b * 64 + tid]; tot[tid] = (float)SS * sy0[tid] + ws[O_GD + tid]; }
    for (int n = tid; n < 768; n += 256) shts[n] = ws[O_HS + n];
    __syncthreads();

    for (int n = tid; n < 1664; n += 256) {
        int base2, k;
        if (n < 192)      { base2 = 0;   k = 3; }
        else if (n < 512) { base2 = 192; k = 5; }
        else if (n < 960) { base2 = 512; k = 7; }
        else              { base2 = 960; k = 11; }
        const int m = n - base2, i = m / k, j = m - i * k, d = j - (k >> 1);
        float corr = 0.f;
        if (d > 0)      corr = (float)d * sy0[i] + shts[d * 64 + i];
        else if (d < 0) corr = (float)(-d) * sy0[i] + shts[(6 - d) * 64 + i];
        V[n] = tot[i] - corr;
    }
    __syncthreads();

    for (int qq = 0; qq < 16; ++qq) {
        const int o = wv * 16 + qq;
        float acc = 0.f;
        #pragma unroll
        for (int r = 0; r < 3; ++r)  { const int m = r * 64 + lane; acc = fmaf(K3[o * 192 + m],  V[m],       acc); }
        #pragma unroll
        for (int r = 0; r < 5; ++r)  { const int m = r * 64 + lane; acc = fmaf(K5[o * 320 + m],  V[192 + m], acc); }
        #pragma unroll
        for (int r = 0; r < 7; ++r)  { const int m = r * 64 + lane; acc = fmaf(K7[o * 448 + m],  V[512 + m], acc); }
        #pragma unroll
        for (int r = 0; r < 11; ++r) { const int m = r * 64 + lane; acc = fmaf(K11[o * 704 + m], V[960 + m], acc); }
        #pragma unroll
        for (int d2 = 32; d2; d2 >>= 1) acc += __shfl_xor(acc, d2);
        if (lane == 0) {
            const float cb = c3[o] + c5[o] + c7[o] + c11[o];
            feat[o] = 0.25f * (acc * (1.0f / (float)SS) + cb);
        }
    }
    __syncthreads();

    if (tid < 64) {
        float g = hb1[lane];
        for (int o = 0; o < 64; ++o) g = fmaf(feat[o], H1[o * 64 + lane], g);
        g = fmaxf(g, 0.f);
        float v = g * H2[lane];
        #pragma unroll
        for (int d2 = 32; d2; d2 >>= 1) v += __shfl_xor(v, d2);
        if (lane == 0) hurst[b] = 1.f / (1.f + expf(-(v + hb2[0])));
    }
}

extern "C" void kernel_launch(void* const* d_in, const int* in_sizes, int n_in,
                              void* d_out, int out_size, void* d_ws, size_t ws_size,
                              hipStream_t stream)
{
    const float* t   = (const float*)d_in[0];
    const float* y0  = (const float*)d_in[1];
    const float* W1  = (const float*)d_in[2];
    const float* b1  = (const float*)d_in[3];
    const float* W2  = (const float*)d_in[4];
    const float* b2  = (const float*)d_in[5];
    const float* W3  = (const float*)d_in[6];
    const float* b3  = (const float*)d_in[7];
    const float* W4  = (const float*)d_in[8];
    const float* b4  = (const float*)d_in[9];
    const float* K3  = (const float*)d_in[10];
    const float* c3  = (const float*)d_in[11];
    const float* K5  = (const float*)d_in[12];
    const float* c5  = (const float*)d_in[13];
    const float* K7  = (const float*)d_in[14];
    const float* c7  = (const float*)d_in[15];
    const float* K11 = (const float*)d_in[16];
    const float* c11 = (const float*)d_in[17];
    const float* H1  = (const float*)d_in[18];
    const float* hb1 = (const float*)d_in[19];
    const float* H2  = (const float*)d_in[20];
    const float* hb2 = (const float*)d_in[21];

    float* out = (float*)d_out;
    float* ws  = (float*)d_ws;

    hipLaunchKernelGGL(k_rhs, dim3(NCHK), dim3(512), 0, stream,
                       t, W1, b1, W2, b2, W3, b3, W4, b4, ws);
    hipLaunchKernelGGL(k_scan, dim3(1), dim3(1024), 0, stream, ws);
    hipLaunchKernelGGL(k_sol, dim3(2048), dim3(256), 0, stream,
                       (const f32x4*)y0, (const f32x4*)(ws + O_LC),
                       (const f32x4*)(ws + O_OFF), (f32x4*)out);
    hipLaunchKernelGGL(k_feat, dim3(BB), dim3(256), 0, stream,
                       y0, ws, K3, c3, K5, c5, K7, c7, K11, c11,
                       H1, hb1, H2, hb2, out + (size_t)BB * SS * 64);
}

// Round 11
// 220.736 us; speedup vs baseline: 1.7250x; 1.3232x over previous
//
#include <hip/hip_runtime.h>
#include <cmath>

// Problem constants
#define SS 8192
#define BB 64
#define CHK 64          // samples per chunk (per k_rhs block)
#define NCHK 128        // SS / CHK

typedef float __attribute__((ext_vector_type(4))) f32x4;

// ws float offsets
#define O_LC   0u        // lc  [SS][64]   dt * chunk-local inclusive cumsum
#define O_TC   524288u   // Tc  [NCHK][64] dt * chunk total
#define O_LS   532480u   // Ls  [NCHK][64] sum over chunk of lc
#define O_OFF  540672u   // off [NCHK][64] exclusive scan of Tc
#define O_GD   548864u   // Gd  [64]
#define O_HS   548928u   // hsts[12][64]

// ---------------- Kernel A: MLP rhs + chunk-local cumsum (128 blocks x 512) ----------------
// 8 waves; sample = lane (64 samples/block); wave w owns a neuron slice of each
// layer -> weight reads are wave-uniform LDS broadcasts (b128), activations
// stored once per sample.
__global__ __launch_bounds__(512) void k_rhs(
    const float* __restrict__ t,
    const float* __restrict__ W1, const float* __restrict__ b1,
    const float* __restrict__ W2, const float* __restrict__ b2,
    const float* __restrict__ W3, const float* __restrict__ b3,
    const float* __restrict__ W4, const float* __restrict__ b4,
    float* __restrict__ ws)
{
    __shared__ float sW1[64], sb1[64], sb2[128], sb3[64], sb4[64];
    __shared__ float sW2[64 * 128];   // 32 KB
    __shared__ float sW3[128 * 64];   // 32 KB
    __shared__ float sW4[64 * 64];    // 16 KB
    __shared__ float HA[64 * 65];     // h1 (stride 65), later rhs R
    __shared__ float XB[64 * 129];    // h2 (stride 129)
    __shared__ float XC[64 * 65];     // h3
    // ~114 KB -> 1 block/CU, 8 waves

    const int tid = threadIdx.x;
    {   // vectorized staging (16B loads)
        const f32x4* W2v = (const f32x4*)W2;
        const f32x4* W3v = (const f32x4*)W3;
        const f32x4* W4v = (const f32x4*)W4;
        f32x4* sW2v = (f32x4*)sW2;
        f32x4* sW3v = (f32x4*)sW3;
        f32x4* sW4v = (f32x4*)sW4;
        for (int i = tid; i < 2048; i += 512) { sW2v[i] = W2v[i]; sW3v[i] = W3v[i]; }
        for (int i = tid; i < 1024; i += 512) sW4v[i] = W4v[i];
        if (tid < 64) { sW1[tid] = W1[tid]; sb1[tid] = b1[tid];
                        sb3[tid] = b3[tid]; sb4[tid] = b4[tid]; }
        else if (tid < 192) sb2[tid - 64] = b2[tid - 64];
    }
    __syncthreads();

    const int w = tid >> 6, lane = tid & 63;
    const int c = blockIdx.x;
    const int s = c * CHK + lane;
    const float dtv = t[1] - t[0];
    const float tv = t[s];           // t row 0 (identical across batch)

    // layer1: wave w computes h1 cols w*8..w*8+7 for its lane's sample
    #pragma unroll
    for (int j = 0; j < 8; ++j) {
        const int col = w * 8 + j;
        HA[lane * 65 + col] = tanhf(fmaf(tv, sW1[col], sb1[col]));
    }
    __syncthreads();

    // layer2: wave w -> cols [w*16, w*16+16)
    float a2[16];
    #pragma unroll
    for (int j = 0; j < 16; ++j) a2[j] = sb2[w * 16 + j];
    for (int i = 0; i < 64; ++i) {
        const float h = HA[lane * 65 + i];
        const float* wp = &sW2[i * 128 + w * 16];   // wave-uniform -> 4x b128 broadcast
        #pragma unroll
        for (int j = 0; j < 16; ++j) a2[j] = fmaf(h, wp[j], a2[j]);
    }
    #pragma unroll
    for (int j = 0; j < 16; ++j) XB[lane * 129 + w * 16 + j] = tanhf(a2[j]);
    __syncthreads();

    // layer3: wave w -> cols [w*8, w*8+8)
    float a3[8];
    #pragma unroll
    for (int j = 0; j < 8; ++j) a3[j] = sb3[w * 8 + j];
    for (int i = 0; i < 128; ++i) {
        const float h = XB[lane * 129 + i];
        const float* wp = &sW3[i * 64 + w * 8];
        #pragma unroll
        for (int j = 0; j < 8; ++j) a3[j] = fmaf(h, wp[j], a3[j]);
    }
    #pragma unroll
    for (int j = 0; j < 8; ++j) XC[lane * 65 + w * 8 + j] = tanhf(a3[j]);
    __syncthreads();

    // layer4: wave w -> cols [w*8, w*8+8)
    float a4[8];
    #pragma unroll
    for (int j = 0; j < 8; ++j) a4[j] = sb4[w * 8 + j];
    for (int i = 0; i < 64; ++i) {
        const float h = XC[lane * 65 + i];
        const float* wp = &sW4[i * 64 + w * 8];
        #pragma unroll
        for (int j = 0; j < 8; ++j) a4[j] = fmaf(h, wp[j], a4[j]);
    }
    if (s == 0) {                               // rhs row 0 := 0 (cumsum starts at s=1)
        #pragma unroll
        for (int j = 0; j < 8; ++j) a4[j] = 0.f;
    }
    // write rhs R into HA (HA last read pre-XB-barrier -> safe)
    #pragma unroll
    for (int j = 0; j < 8; ++j) HA[lane * 65 + w * 8 + j] = a4[j];
    __syncthreads();

    // chunk-local inclusive cumsum, dt-scaled (wave 0; lane = column)
    if (tid < 64) {
        const int col = tid;
        float run = 0.f, Ls = 0.f;
        for (int jj = 0; jj < CHK; ++jj) {
            run += HA[jj * 65 + col];
            const float v = dtv * run;
            ws[O_LC + (c * CHK + jj) * 64 + col] = v;   // coalesced
            Ls += v;
        }
        ws[O_TC + c * 64 + col] = dtv * run;
        ws[O_LS + c * 64 + col] = Ls;
    }
}

// ---------------- Kernel B: chunk-offset scan + Gd + head/tail (1 block x 1024) ----------------
__global__ __launch_bounds__(1024) void k_scan(float* __restrict__ ws)
{
    __shared__ float gsum[16 * 65];
    __shared__ float offL[64];
    const int tid = threadIdx.x;
    const int col = tid & 63, grp = tid >> 6;   // 16 groups x 8 chunks

    float Tl[8]; float tsum = 0.f;
    #pragma unroll
    for (int k = 0; k < 8; ++k) { Tl[k] = ws[O_TC + (grp * 8 + k) * 64 + col]; tsum += Tl[k]; }
    gsum[grp * 65 + col] = tsum;
    __syncthreads();

    float base = 0.f;
    for (int g = 0; g < grp; ++g) base += gsum[g * 65 + col];   // wave-uniform trip count
    __syncthreads();                                             // reads done before overwrite

    float run = base, gpart = 0.f;
    #pragma unroll
    for (int k = 0; k < 8; ++k) {
        const int cc = grp * 8 + k;
        ws[O_OFF + cc * 64 + col] = run;
        if (cc == NCHK - 1) offL[col] = run;
        gpart += ws[O_LS + cc * 64 + col] + (float)CHK * run;
        run += Tl[k];
    }
    gsum[grp * 65 + col] = gpart;
    __syncthreads();

    if (grp == 0) {
        float g = 0.f;
        #pragma unroll
        for (int gg = 0; gg < 16; ++gg) g += gsum[gg * 65 + col];
        ws[O_GD + col] = g;
    }
    if (grp == 1) {       // hs[d] = sum_{e<d} dtp[e]; chunk 0 offset = 0 -> dtp = lc
        float r2 = 0.f;
        ws[O_HS + col] = 0.f;
        for (int d = 1; d <= 5; ++d) { r2 += ws[O_LC + (d - 1) * 64 + col]; ws[O_HS + d * 64 + col] = r2; }
    }
    if (grp == 2) {       // ts[d] = sum_{e=1..d} dtp[S-e]; dtp = offL + lc
        const float oL = offL[col];
        float r2 = 0.f;
        ws[O_HS + 6 * 64 + col] = 0.f;
        for (int d = 1; d <= 5; ++d) { r2 += oL + ws[O_LC + (SS - d) * 64 + col]; ws[O_HS + (6 + d) * 64 + col] = r2; }
    }
}

// ---------------- Kernel C: sol[b,s,:] = y0[b,:] + off[c(s),:] + lc[s,:] ----------------
// 2048 blocks x 256. Thread owns one (s,i4), reads lc+off ONCE, walks 16 b's.
__global__ __launch_bounds__(256) void k_sol(const f32x4* __restrict__ y04,
                                             const f32x4* __restrict__ lc4,
                                             const f32x4* __restrict__ off4,
                                             f32x4* __restrict__ out4)
{
    const int gtid = blockIdx.x * 256 + threadIdx.x;   // 524288 threads
    const int si = gtid & 131071;                      // s = si>>4, i4 = si&15
    const int bg = gtid >> 17;                         // 0..3
    const int i4 = si & 15;
    const int s  = si >> 4;
    const f32x4 pf = lc4[si] + off4[(s >> 6) * 16 + i4];
    #pragma unroll
    for (int k = 0; k < 16; ++k) {
        const int b = bg * 16 + k;
        out4[b * 131072 + si] = y04[b * 16 + i4] + pf;
    }
}

// ---------------- Kernel D: analytic conv-mean features + hurst (64 blocks x 256) ----------------
__global__ __launch_bounds__(256) void k_feat(
    const float* __restrict__ y0, const float* __restrict__ ws,
    const float* __restrict__ K3, const float* __restrict__ c3,
    const float* __restrict__ K5, const float* __restrict__ c5,
    const float* __restrict__ K7, const float* __restrict__ c7,
    const float* __restrict__ K11, const float* __restrict__ c11,
    const float* __restrict__ H1, const float* __restrict__ hb1,
    const float* __restrict__ H2, const float* __restrict__ hb2,
    float* __restrict__ hurst)
{
    __shared__ float tot[64], sy0[64], shts[12 * 64], V[1664], feat[64];
    const int b = blockIdx.x, tid = threadIdx.x;
    const int wv = tid >> 6, lane = tid & 63;

    if (tid < 64) { sy0[tid] = y0[b * 64 + tid]; tot[tid] = (float)SS * sy0[tid] + ws[O_GD + tid]; }
    for (int n = tid; n < 768; n += 256) shts[n] = ws[O_HS + n];
    __syncthreads();

    for (int n = tid; n < 1664; n += 256) {
        int base2, k;
        if (n < 192)      { base2 = 0;   k = 3; }
        else if (n < 512) { base2 = 192; k = 5; }
        else if (n < 960) { base2 = 512; k = 7; }
        else              { base2 = 960; k = 11; }
        const int m = n - base2, i = m / k, j = m - i * k, d = j - (k >> 1);
        float corr = 0.f;
        if (d > 0)      corr = (float)d * sy0[i] + shts[d * 64 + i];
        else if (d < 0) corr = (float)(-d) * sy0[i] + shts[(6 - d) * 64 + i];
        V[n] = tot[i] - corr;
    }
    __syncthreads();

    for (int qq = 0; qq < 16; ++qq) {
        const int o = wv * 16 + qq;
        float acc = 0.f;
        #pragma unroll
        for (int r = 0; r < 3; ++r)  { const int m = r * 64 + lane; acc = fmaf(K3[o * 192 + m],  V[m],       acc); }
        #pragma unroll
        for (int r = 0; r < 5; ++r)  { const int m = r * 64 + lane; acc = fmaf(K5[o * 320 + m],  V[192 + m], acc); }
        #pragma unroll
        for (int r = 0; r < 7; ++r)  { const int m = r * 64 + lane; acc = fmaf(K7[o * 448 + m],  V[512 + m], acc); }
        #pragma unroll
        for (int r = 0; r < 11; ++r) { const int m = r * 64 + lane; acc = fmaf(K11[o * 704 + m], V[960 + m], acc); }
        #pragma unroll
        for (int d2 = 32; d2; d2 >>= 1) acc += __shfl_xor(acc, d2);
        if (lane == 0) {
            const float cb = c3[o] + c5[o] + c7[o] + c11[o];
            feat[o] = 0.25f * (acc * (1.0f / (float)SS) + cb);
        }
    }
    __syncthreads();

    if (tid < 64) {
        float g = hb1[lane];
        for (int o = 0; o < 64; ++o) g = fmaf(feat[o], H1[o * 64 + lane], g);
        g = fmaxf(g, 0.f);
        float v = g * H2[lane];
        #pragma unroll
        for (int d2 = 32; d2; d2 >>= 1) v += __shfl_xor(v, d2);
        if (lane == 0) hurst[b] = 1.f / (1.f + expf(-(v + hb2[0])));
    }
}

extern "C" void kernel_launch(void* const* d_in, const int* in_sizes, int n_in,
                              void* d_out, int out_size, void* d_ws, size_t ws_size,
                              hipStream_t stream)
{
    const float* t   = (const float*)d_in[0];
    const float* y0  = (const float*)d_in[1];
    const float* W1  = (const float*)d_in[2];
    const float* b1  = (const float*)d_in[3];
    const float* W2  = (const float*)d_in[4];
    const float* b2  = (const float*)d_in[5];
    const float* W3  = (const float*)d_in[6];
    const float* b3  = (const float*)d_in[7];
    const float* W4  = (const float*)d_in[8];
    const float* b4  = (const float*)d_in[9];
    const float* K3  = (const float*)d_in[10];
    const float* c3  = (const float*)d_in[11];
    const float* K5  = (const float*)d_in[12];
    const float* c5  = (const float*)d_in[13];
    const float* K7  = (const float*)d_in[14];
    const float* c7  = (const float*)d_in[15];
    const float* K11 = (const float*)d_in[16];
    const float* c11 = (const float*)d_in[17];
    const float* H1  = (const float*)d_in[18];
    const float* hb1 = (const float*)d_in[19];
    const float* H2  = (const float*)d_in[20];
    const float* hb2 = (const float*)d_in[21];

    float* out = (float*)d_out;
    float* ws  = (float*)d_ws;

    hipLaunchKernelGGL(k_rhs, dim3(NCHK), dim3(512), 0, stream,
                       t, W1, b1, W2, b2, W3, b3, W4, b4, ws);
    hipLaunchKernelGGL(k_scan, dim3(1), dim3(1024), 0, stream, ws);
    hipLaunchKernelGGL(k_sol, dim3(2048), dim3(256), 0, stream,
                       (const f32x4*)y0, (const f32x4*)(ws + O_LC),
                       (const f32x4*)(ws + O_OFF), (f32x4*)out);
    hipLaunchKernelGGL(k_feat, dim3(BB), dim3(256), 0, stream,
                       y0, ws, K3, c3, K5, c5, K7, c7, K11, c11,
                       H1, hb1, H2, hb2, out + (size_t)BB * SS * 64);
}